// Round 4
// baseline (1633.846 us; speedup 1.0000x reference)
//
#include <hip/hip_runtime.h>

#define IN_DIM 512
#define OUT_DIM 32
#define KSTEPS 10
#define ALPHA 0.1f
#define NT 128       // nodes per gemm block
#define KH 256       // K half per thread
#define KC 32        // staged K chunk

// ---------------- degree / norm / chunked-CSR build ----------------
// CSR buckets keyed by (dst, src_chunk): 4 chunks of ~N/4 src nodes so the
// gather working set per phase (~3.2MB of z) is L2-resident.

__global__ void k_count(const int* __restrict__ src, const int* __restrict__ dst,
                        int* __restrict__ cnt, int E, int cdiv) {
    int e = blockIdx.x * blockDim.x + threadIdx.x;
    if (e < E) {
        int ch = src[e] / cdiv;
        atomicAdd(&cnt[dst[e] * 4 + ch], 1);
    }
}

__global__ void k_rsqrt(const int* __restrict__ cnt, float* __restrict__ dinv, int N) {
    int i = blockIdx.x * blockDim.x + threadIdx.x;
    if (i < N) {
        int deg = cnt[4 * i] + cnt[4 * i + 1] + cnt[4 * i + 2] + cnt[4 * i + 3];
        dinv[i] = rsqrtf((float)deg + 1.0f);  // +1 self-loop
    }
}

// Exclusive prefix sum over M counts, single workgroup of 1024 threads.
__global__ __launch_bounds__(1024) void k_scan(const int* __restrict__ cnt,
                                               int* __restrict__ off, int M) {
    __shared__ int partials[1024];
    int t = threadIdx.x;
    int chunk = (M + 1023) / 1024;
    int lo = t * chunk;
    int hi = lo + chunk; if (hi > M) hi = M; if (lo > M) lo = M;
    int s = 0;
    for (int i = lo; i < hi; i++) s += cnt[i];
    partials[t] = s;
    __syncthreads();
    for (int d = 1; d < 1024; d <<= 1) {
        int v = (t >= d) ? partials[t - d] : 0;
        __syncthreads();
        partials[t] += v;
        __syncthreads();
    }
    int base = (t == 0) ? 0 : partials[t - 1];
    for (int i = lo; i < hi; i++) { off[i] = base; base += cnt[i]; }
    if (t == 0) off[M] = partials[1023];
}

__global__ void k_fill(const int* __restrict__ src, const int* __restrict__ dst,
                       const float* __restrict__ dinv, const int* __restrict__ off4,
                       int* __restrict__ cur, float2* __restrict__ csr, int E, int cdiv) {
    int e = blockIdx.x * blockDim.x + threadIdx.x;
    if (e < E) {
        int d = dst[e], s = src[e];
        int key = d * 4 + s / cdiv;
        int pos = off4[key] + atomicAdd(&cur[key], 1);
        csr[pos] = make_float2(dinv[s] * dinv[d], __int_as_float(s));
    }
}

// ---------------- dense projection h = x @ W^T + b ----------------
// LDS-staged: coalesced 128B global segments into a padded tile, fixing the
// 2.9x HBM over-fetch of the direct thread-per-node pattern.
// half = (t>>6)&1 is WAVE-UNIFORM so W indexing stays on the scalar path.

__global__ __launch_bounds__(256) void k_gemm2(const float* __restrict__ x,
                                               const float* __restrict__ W,
                                               const float* __restrict__ bias,
                                               float* __restrict__ h, int N) {
    __shared__ float tile[256 * 33];  // virtual row r=(node_local*2+half), pad 33
    int t = threadIdx.x;
    int n0 = blockIdx.x * NT;
    int hc = (t >> 6) & 1;                       // wave-uniform K-half
    int nl = (t & 63) + ((t >> 7) << 6);         // node_local 0..127
    int myrow = nl * 2 + hc;
    const float* Wk = W + hc * KH;               // scalar-path base

    float acc[OUT_DIM];
#pragma unroll
    for (int o = 0; o < OUT_DIM; o++) acc[o] = 0.0f;

    for (int kc = 0; kc < KH / KC; kc++) {
        __syncthreads();
        // stage 256 rows x 32 cols: 8 float4/thread, coalesced 128B segments
#pragma unroll
        for (int i = 0; i < 8; i++) {
            int f = i * 256 + t;
            int r = f >> 3, c4 = f & 7;
            int gn = n0 + (r >> 1); if (gn >= N) gn = N - 1;
            float4 v = *(const float4*)(x + (size_t)gn * IN_DIM + (r & 1) * KH + kc * KC + c4 * 4);
            float* dp = &tile[r * 33 + c4 * 4];
            dp[0] = v.x; dp[1] = v.y; dp[2] = v.z; dp[3] = v.w;
        }
        __syncthreads();
        const float* row = &tile[myrow * 33];
#pragma unroll 4
        for (int k = 0; k < KC; k++) {
            float xv = row[k];
#pragma unroll
            for (int o = 0; o < OUT_DIM; o++)
                acc[o] = fmaf(xv, Wk[(size_t)o * IN_DIM + kc * KC + k], acc[o]);
        }
    }

    // combine the two K-halves through LDS (partner is in another wave)
    __syncthreads();
    if (hc == 1) {
#pragma unroll
        for (int o = 0; o < OUT_DIM; o++) tile[nl * 33 + o] = acc[o];
    }
    __syncthreads();
    int node = n0 + nl;
    if (hc == 0 && node < N) {
        float4* out = (float4*)(h + (size_t)node * OUT_DIM);
#pragma unroll
        for (int o4 = 0; o4 < 8; o4++) {
            float s0 = acc[4 * o4 + 0] + tile[nl * 33 + 4 * o4 + 0] + bias[4 * o4 + 0];
            float s1 = acc[4 * o4 + 1] + tile[nl * 33 + 4 * o4 + 1] + bias[4 * o4 + 1];
            float s2 = acc[4 * o4 + 2] + tile[nl * 33 + 4 * o4 + 2] + bias[4 * o4 + 2];
            float s3 = acc[4 * o4 + 3] + tile[nl * 33 + 4 * o4 + 3] + bias[4 * o4 + 3];
            out[o4] = make_float4(s0, s1, s2, s3);
        }
    }
}

// ---------------- propagation: pull, float4 per lane ----------------
// 8 lanes per dst node, each lane owns 4 channels: one gather instr = one
// fully-used 128B line. Unroll-2 for memory-level parallelism.

__global__ __launch_bounds__(256) void k_pull(const int* __restrict__ off4,
                                              const float2* __restrict__ csr,
                                              const float* __restrict__ zprev,
                                              const float* __restrict__ h,
                                              const float* __restrict__ dinv,
                                              float* __restrict__ znext, int N) {
    int t = blockIdx.x * 256 + threadIdx.x;
    int node = t >> 3;
    int l = (t & 7) * 4;  // first of this lane's 4 channels
    if (node >= N) return;
    int beg = off4[node * 4];
    int end = off4[node * 4 + 4];
    float a00 = 0.f, a01 = 0.f, a02 = 0.f, a03 = 0.f;
    float a10 = 0.f, a11 = 0.f, a12 = 0.f, a13 = 0.f;
    int j = beg;
    for (; j + 2 <= end; j += 2) {
        float2 r0 = csr[j];
        float2 r1 = csr[j + 1];
        float4 z0 = *(const float4*)(zprev + (size_t)__float_as_int(r0.y) * OUT_DIM + l);
        float4 z1 = *(const float4*)(zprev + (size_t)__float_as_int(r1.y) * OUT_DIM + l);
        a00 = fmaf(r0.x, z0.x, a00); a01 = fmaf(r0.x, z0.y, a01);
        a02 = fmaf(r0.x, z0.z, a02); a03 = fmaf(r0.x, z0.w, a03);
        a10 = fmaf(r1.x, z1.x, a10); a11 = fmaf(r1.x, z1.y, a11);
        a12 = fmaf(r1.x, z1.z, a12); a13 = fmaf(r1.x, z1.w, a13);
    }
    if (j < end) {
        float2 r = csr[j];
        float4 z = *(const float4*)(zprev + (size_t)__float_as_int(r.y) * OUT_DIM + l);
        a00 = fmaf(r.x, z.x, a00); a01 = fmaf(r.x, z.y, a01);
        a02 = fmaf(r.x, z.z, a02); a03 = fmaf(r.x, z.w, a03);
    }
    float d = dinv[node];
    float d2 = d * d;
    float4 zs = *(const float4*)(zprev + (size_t)node * OUT_DIM + l);
    float4 hh = *(const float4*)(h + (size_t)node * OUT_DIM + l);
    float s0 = a00 + a10 + d2 * zs.x;
    float s1 = a01 + a11 + d2 * zs.y;
    float s2 = a02 + a12 + d2 * zs.z;
    float s3 = a03 + a13 + d2 * zs.w;
    float4 res = make_float4(fmaf(1.0f - ALPHA, s0, ALPHA * hh.x),
                             fmaf(1.0f - ALPHA, s1, ALPHA * hh.y),
                             fmaf(1.0f - ALPHA, s2, ALPHA * hh.z),
                             fmaf(1.0f - ALPHA, s3, ALPHA * hh.w));
    *(float4*)(znext + (size_t)node * OUT_DIM + l) = res;
}

extern "C" void kernel_launch(void* const* d_in, const int* in_sizes, int n_in,
                              void* d_out, int out_size, void* d_ws, size_t ws_size,
                              hipStream_t stream) {
    const float* x    = (const float*)d_in[0];
    const float* W    = (const float*)d_in[1];
    const float* bias = (const float*)d_in[2];
    const int*   ei   = (const int*)d_in[3];

    const int N = in_sizes[0] / IN_DIM;   // 100000
    const int E = in_sizes[3] / 2;        // 1600000
    const int* src = ei;
    const int* dst = ei + E;
    const int cdiv = (N + 3) / 4;         // src-chunk width

    // workspace layout (16B-aligned pieces)
    char* ws = (char*)d_ws;
    size_t o = 0;
    float*  h    = (float*)(ws + o);  o += (size_t)N * OUT_DIM * 4;      // 12.8 MB
    float*  A    = (float*)(ws + o);  o += (size_t)N * OUT_DIM * 4;      // 12.8 MB
    float2* csr  = (float2*)(ws + o); o += (size_t)E * 8;                // 12.8 MB
    float*  dinv = (float*)(ws + o);  o += (size_t)N * 4;
    int*    off4 = (int*)(ws + o);    o += (size_t)(4 * N + 1) * 4;
    int*    cnt  = (int*)(ws + o);    o += (size_t)4 * N * 4;
    int*    cur  = (int*)(ws + o);    o += (size_t)4 * N * 4;

    const int B = 256;
    int gN  = (N + B - 1) / B;
    int gE  = (E + B - 1) / B;
    int gP  = ((size_t)N * 8 + B - 1) / B;          // pull grid (3125)
    int gG  = (N + NT - 1) / NT;                    // gemm grid (782)

    hipMemsetAsync(cnt, 0, (size_t)8 * N * 4, stream);  // zeros cnt AND cur (adjacent)

    // degree + norm + chunked CSR
    k_count<<<gE, B, 0, stream>>>(src, dst, cnt, E, cdiv);
    k_rsqrt<<<gN, B, 0, stream>>>(cnt, dinv, N);
    k_scan<<<1, 1024, 0, stream>>>(cnt, off4, 4 * N);
    k_fill<<<gE, B, 0, stream>>>(src, dst, dinv, off4, cur, csr, E, cdiv);

    // dense projection
    k_gemm2<<<gG, B, 0, stream>>>(x, W, bias, h, N);

    // K propagation steps; ping-pong A <-> d_out so step 10 lands in d_out
    const float* zprev = h;
    for (int s = 0; s < KSTEPS; s++) {
        float* znext = (s % 2 == 0) ? A : (float*)d_out;
        k_pull<<<gP, B, 0, stream>>>(off4, csr, zprev, h, dinv, znext, N);
        zprev = znext;
    }
}

// Round 5
// 1616.880 us; speedup vs baseline: 1.0105x; 1.0105x over previous
//
#include <hip/hip_runtime.h>

#define IN_DIM 512
#define OUT_DIM 32
#define KSTEPS 10
#define ALPHA 0.1f
#define NT 128       // nodes per gemm block
#define KH 256       // K half per thread
#define KC 32        // staged K chunk
#define SCB 512      // scan block chunk
#define DBK 1024     // degree buckets

// ---------------- degree / norm / chunked-CSR build ----------------

__global__ void k_count(const int* __restrict__ src, const int* __restrict__ dst,
                        int* __restrict__ cnt, int E, int cdiv) {
    int e = blockIdx.x * blockDim.x + threadIdx.x;
    if (e < E) {
        int ch = src[e] / cdiv;
        atomicAdd(&cnt[dst[e] * 4 + ch], 1);
    }
}

// dinv + integer degree + degree histogram (for the degree-sort permutation)
__global__ void k_rsqrt(const int* __restrict__ cnt, float* __restrict__ dinv,
                        int* __restrict__ deg, int* __restrict__ hist, int N) {
    int i = blockIdx.x * blockDim.x + threadIdx.x;
    if (i < N) {
        int d = cnt[4 * i] + cnt[4 * i + 1] + cnt[4 * i + 2] + cnt[4 * i + 3];
        dinv[i] = rsqrtf((float)d + 1.0f);  // +1 self-loop
        int b = d < DBK ? d : DBK - 1;
        deg[i] = b;
        atomicAdd(&hist[b], 1);
    }
}

// ---------------- parallel exclusive scan (3 phases) ----------------

__global__ __launch_bounds__(SCB) void k_bsum(const int* __restrict__ v,
                                              int* __restrict__ bsum, int M) {
    __shared__ int s[SCB];
    int i = blockIdx.x * SCB + threadIdx.x;
    s[threadIdx.x] = (i < M) ? v[i] : 0;
    __syncthreads();
    for (int d = SCB / 2; d > 0; d >>= 1) {
        if (threadIdx.x < d) s[threadIdx.x] += s[threadIdx.x + d];
        __syncthreads();
    }
    if (threadIdx.x == 0) bsum[blockIdx.x] = s[0];
}

// single block: exclusive scan of NB block sums (NB <= 1024); also writes total.
__global__ __launch_bounds__(1024) void k_bscan(const int* __restrict__ bsum,
                                                int* __restrict__ bsum_off,
                                                int* __restrict__ total_out, int NB) {
    __shared__ int s[1024];
    int t = threadIdx.x;
    s[t] = (t < NB) ? bsum[t] : 0;
    __syncthreads();
    for (int d = 1; d < 1024; d <<= 1) {
        int v = (t >= d) ? s[t - d] : 0;
        __syncthreads();
        s[t] += v;
        __syncthreads();
    }
    if (t < NB) bsum_off[t] = (t == 0) ? 0 : s[t - 1];
    if (t == 0 && total_out) *total_out = s[1023];
}

__global__ __launch_bounds__(SCB) void k_boff(const int* __restrict__ v,
                                              const int* __restrict__ bsum_off,
                                              int* __restrict__ off, int M) {
    __shared__ int s[SCB];
    int t = threadIdx.x;
    int i = blockIdx.x * SCB + t;
    int myv = (i < M) ? v[i] : 0;
    s[t] = myv;
    __syncthreads();
    for (int d = 1; d < SCB; d <<= 1) {
        int u = (t >= d) ? s[t - d] : 0;
        __syncthreads();
        s[t] += u;
        __syncthreads();
    }
    if (i < M) off[i] = bsum_off[blockIdx.x] + s[t] - myv;  // exclusive
}

// ---------------- permutation fill (counting sort by degree) ----------------

__global__ void k_perm(const int* __restrict__ deg, const int* __restrict__ hoff,
                       int* __restrict__ hcur, int* __restrict__ perm, int N) {
    int i = blockIdx.x * blockDim.x + threadIdx.x;
    if (i < N) {
        int b = deg[i];
        int pos = hoff[b] + atomicAdd(&hcur[b], 1);
        perm[pos] = i;
    }
}

__global__ void k_fill(const int* __restrict__ src, const int* __restrict__ dst,
                       const float* __restrict__ dinv, const int* __restrict__ off4,
                       int* __restrict__ cur, float2* __restrict__ csr, int E, int cdiv) {
    int e = blockIdx.x * blockDim.x + threadIdx.x;
    if (e < E) {
        int d = dst[e], s = src[e];
        int key = d * 4 + s / cdiv;
        int pos = off4[key] + atomicAdd(&cur[key], 1);
        csr[pos] = make_float2(dinv[s] * dinv[d], __int_as_float(s));
    }
}

// ---------------- dense projection h = x @ W^T + b (LDS-staged) ----------------

__global__ __launch_bounds__(256) void k_gemm2(const float* __restrict__ x,
                                               const float* __restrict__ W,
                                               const float* __restrict__ bias,
                                               float* __restrict__ h, int N) {
    __shared__ float tile[256 * 33];
    int t = threadIdx.x;
    int n0 = blockIdx.x * NT;
    int hc = (t >> 6) & 1;                       // wave-uniform K-half
    int nl = (t & 63) + ((t >> 7) << 6);         // node_local 0..127
    int myrow = nl * 2 + hc;
    const float* Wk = W + hc * KH;

    float acc[OUT_DIM];
#pragma unroll
    for (int o = 0; o < OUT_DIM; o++) acc[o] = 0.0f;

    for (int kc = 0; kc < KH / KC; kc++) {
        __syncthreads();
#pragma unroll
        for (int i = 0; i < 8; i++) {
            int f = i * 256 + t;
            int r = f >> 3, c4 = f & 7;
            int gn = n0 + (r >> 1); if (gn >= N) gn = N - 1;
            float4 v = *(const float4*)(x + (size_t)gn * IN_DIM + (r & 1) * KH + kc * KC + c4 * 4);
            float* dp = &tile[r * 33 + c4 * 4];
            dp[0] = v.x; dp[1] = v.y; dp[2] = v.z; dp[3] = v.w;
        }
        __syncthreads();
        const float* row = &tile[myrow * 33];
#pragma unroll 4
        for (int k = 0; k < KC; k++) {
            float xv = row[k];
#pragma unroll
            for (int o = 0; o < OUT_DIM; o++)
                acc[o] = fmaf(xv, Wk[(size_t)o * IN_DIM + kc * KC + k], acc[o]);
        }
    }

    __syncthreads();
    if (hc == 1) {
#pragma unroll
        for (int o = 0; o < OUT_DIM; o++) tile[nl * 33 + o] = acc[o];
    }
    __syncthreads();
    int node = n0 + nl;
    if (hc == 0 && node < N) {
        float4* out = (float4*)(h + (size_t)node * OUT_DIM);
#pragma unroll
        for (int o4 = 0; o4 < 8; o4++) {
            out[o4] = make_float4(acc[4 * o4 + 0] + tile[nl * 33 + 4 * o4 + 0] + bias[4 * o4 + 0],
                                  acc[4 * o4 + 1] + tile[nl * 33 + 4 * o4 + 1] + bias[4 * o4 + 1],
                                  acc[4 * o4 + 2] + tile[nl * 33 + 4 * o4 + 2] + bias[4 * o4 + 2],
                                  acc[4 * o4 + 3] + tile[nl * 33 + 4 * o4 + 3] + bias[4 * o4 + 3]);
        }
    }
}

// ---------------- propagation: pull, float4/lane, degree-sorted ----------------
// rank -> node via degree-sorted perm: the 8 nodes of a wave have near-equal
// degree -> near-zero loop divergence.

__global__ __launch_bounds__(256) void k_pull(const int* __restrict__ perm,
                                              const int* __restrict__ off4,
                                              const float2* __restrict__ csr,
                                              const float* __restrict__ zprev,
                                              const float* __restrict__ h,
                                              const float* __restrict__ dinv,
                                              float* __restrict__ znext, int N) {
    int t = blockIdx.x * 256 + threadIdx.x;
    int rank = t >> 3;
    int l = (t & 7) * 4;
    if (rank >= N) return;
    int node = perm[rank];
    int beg = off4[node * 4];
    int end = off4[node * 4 + 4];
    float a00 = 0.f, a01 = 0.f, a02 = 0.f, a03 = 0.f;
    float a10 = 0.f, a11 = 0.f, a12 = 0.f, a13 = 0.f;
    int j = beg;
    for (; j + 2 <= end; j += 2) {
        float2 r0 = csr[j];
        float2 r1 = csr[j + 1];
        float4 z0 = *(const float4*)(zprev + (size_t)__float_as_int(r0.y) * OUT_DIM + l);
        float4 z1 = *(const float4*)(zprev + (size_t)__float_as_int(r1.y) * OUT_DIM + l);
        a00 = fmaf(r0.x, z0.x, a00); a01 = fmaf(r0.x, z0.y, a01);
        a02 = fmaf(r0.x, z0.z, a02); a03 = fmaf(r0.x, z0.w, a03);
        a10 = fmaf(r1.x, z1.x, a10); a11 = fmaf(r1.x, z1.y, a11);
        a12 = fmaf(r1.x, z1.z, a12); a13 = fmaf(r1.x, z1.w, a13);
    }
    if (j < end) {
        float2 r = csr[j];
        float4 z = *(const float4*)(zprev + (size_t)__float_as_int(r.y) * OUT_DIM + l);
        a00 = fmaf(r.x, z.x, a00); a01 = fmaf(r.x, z.y, a01);
        a02 = fmaf(r.x, z.z, a02); a03 = fmaf(r.x, z.w, a03);
    }
    float d = dinv[node];
    float d2 = d * d;
    float4 zs = *(const float4*)(zprev + (size_t)node * OUT_DIM + l);
    float4 hh = *(const float4*)(h + (size_t)node * OUT_DIM + l);
    float s0 = a00 + a10 + d2 * zs.x;
    float s1 = a01 + a11 + d2 * zs.y;
    float s2 = a02 + a12 + d2 * zs.z;
    float s3 = a03 + a13 + d2 * zs.w;
    float4 res = make_float4(fmaf(1.0f - ALPHA, s0, ALPHA * hh.x),
                             fmaf(1.0f - ALPHA, s1, ALPHA * hh.y),
                             fmaf(1.0f - ALPHA, s2, ALPHA * hh.z),
                             fmaf(1.0f - ALPHA, s3, ALPHA * hh.w));
    *(float4*)(znext + (size_t)node * OUT_DIM + l) = res;
}

extern "C" void kernel_launch(void* const* d_in, const int* in_sizes, int n_in,
                              void* d_out, int out_size, void* d_ws, size_t ws_size,
                              hipStream_t stream) {
    const float* x    = (const float*)d_in[0];
    const float* W    = (const float*)d_in[1];
    const float* bias = (const float*)d_in[2];
    const int*   ei   = (const int*)d_in[3];

    const int N = in_sizes[0] / IN_DIM;   // 100000
    const int E = in_sizes[3] / 2;        // 1600000
    const int* src = ei;
    const int* dst = ei + E;
    const int cdiv = (N + 3) / 4;
    const int M = 4 * N;                  // scan length
    const int NB = (M + SCB - 1) / SCB;   // scan blocks (782)

    // workspace layout (16B-aligned pieces first)
    char* ws = (char*)d_ws;
    size_t o = 0;
    float*  h    = (float*)(ws + o);  o += (size_t)N * OUT_DIM * 4;      // 12.8 MB
    float*  A    = (float*)(ws + o);  o += (size_t)N * OUT_DIM * 4;      // 12.8 MB
    float2* csr  = (float2*)(ws + o); o += (size_t)E * 8;                // 12.8 MB
    float*  dinv = (float*)(ws + o);  o += (size_t)N * 4;
    int*    off4 = (int*)(ws + o);    o += (size_t)(M + 1) * 4;
    int*    cnt  = (int*)(ws + o);    o += (size_t)M * 4;
    int*    cur  = (int*)(ws + o);    o += (size_t)M * 4;
    int*    deg  = (int*)(ws + o);    o += (size_t)N * 4;
    int*    perm = (int*)(ws + o);    o += (size_t)N * 4;
    int*    bsum = (int*)(ws + o);    o += (size_t)NB * 4;
    int*    boff = (int*)(ws + o);    o += (size_t)NB * 4;
    int*    hist = (int*)(ws + o);    o += (size_t)DBK * 4;
    int*    hoff = (int*)(ws + o);    o += (size_t)DBK * 4;
    int*    hcur = (int*)(ws + o);    o += (size_t)DBK * 4;

    const int B = 256;
    int gN = (N + B - 1) / B;
    int gE = (E + B - 1) / B;
    int gP = ((size_t)N * 8 + B - 1) / B;   // pull grid (3125)
    int gG = (N + NT - 1) / NT;             // gemm grid (782)

    hipMemsetAsync(cnt, 0, (size_t)2 * M * 4, stream);       // cnt + cur (adjacent)
    hipMemsetAsync(hist, 0, (size_t)3 * DBK * 4, stream);    // hist + hoff + hcur

    // degree + norm + histogram
    k_count<<<gE, B, 0, stream>>>(src, dst, cnt, E, cdiv);
    k_rsqrt<<<gN, B, 0, stream>>>(cnt, dinv, deg, hist, N);

    // parallel exclusive scan of cnt -> off4 (+ total at off4[M])
    k_bsum<<<NB, SCB, 0, stream>>>(cnt, bsum, M);
    k_bscan<<<1, 1024, 0, stream>>>(bsum, boff, off4 + M, NB);
    k_boff<<<NB, SCB, 0, stream>>>(cnt, boff, off4, M);

    // degree-bucket scan (1024 entries, single block) + permutation
    k_bscan<<<1, 1024, 0, stream>>>(hist, hoff, (int*)nullptr, DBK);
    k_perm<<<gN, B, 0, stream>>>(deg, hoff, hcur, perm, N);

    // CSR fill
    k_fill<<<gE, B, 0, stream>>>(src, dst, dinv, off4, cur, csr, E, cdiv);

    // dense projection
    k_gemm2<<<gG, B, 0, stream>>>(x, W, bias, h, N);

    // K propagation steps; ping-pong A <-> d_out so step 10 lands in d_out
    const float* zprev = h;
    for (int s = 0; s < KSTEPS; s++) {
        float* znext = (s % 2 == 0) ? A : (float*)d_out;
        k_pull<<<gP, B, 0, stream>>>(perm, off4, csr, zprev, h, dinv, znext, N);
        zprev = znext;
    }
}

// Round 6
// 769.197 us; speedup vs baseline: 2.1241x; 2.1020x over previous
//
#include <hip/hip_runtime.h>

#define IN_DIM 512
#define OUT_DIM 32
#define KSTEPS 10
#define ALPHA 0.1f
#define SCB 512      // scan block chunk

typedef __attribute__((ext_vector_type(8))) short short8;   // 8 bf16 (4 VGPRs)
typedef __attribute__((ext_vector_type(4))) float floatx4;  // MFMA acc

// ---------------- degree / norm / chunked-CSR build ----------------
// CSR buckets keyed by (dst, src_chunk): 4 chunks so each phase's gather
// window of z (~3.2MB) is L2-friendly. Processed in NODE ORDER (no perm —
// R5 showed the degree-sort perm doubled pull time by killing locality).

__global__ void k_count(const int* __restrict__ src, const int* __restrict__ dst,
                        int* __restrict__ cnt, int E, int cdiv) {
    int e = blockIdx.x * blockDim.x + threadIdx.x;
    if (e < E) {
        int ch = src[e] / cdiv;
        atomicAdd(&cnt[dst[e] * 4 + ch], 1);
    }
}

__global__ void k_rsqrt(const int* __restrict__ cnt, float* __restrict__ dinv, int N) {
    int i = blockIdx.x * blockDim.x + threadIdx.x;
    if (i < N) {
        int d = cnt[4 * i] + cnt[4 * i + 1] + cnt[4 * i + 2] + cnt[4 * i + 3];
        dinv[i] = rsqrtf((float)d + 1.0f);  // +1 self-loop
    }
}

// ---------------- parallel exclusive scan (3 phases) ----------------

__global__ __launch_bounds__(SCB) void k_bsum(const int* __restrict__ v,
                                              int* __restrict__ bsum, int M) {
    __shared__ int s[SCB];
    int i = blockIdx.x * SCB + threadIdx.x;
    s[threadIdx.x] = (i < M) ? v[i] : 0;
    __syncthreads();
    for (int d = SCB / 2; d > 0; d >>= 1) {
        if (threadIdx.x < d) s[threadIdx.x] += s[threadIdx.x + d];
        __syncthreads();
    }
    if (threadIdx.x == 0) bsum[blockIdx.x] = s[0];
}

__global__ __launch_bounds__(1024) void k_bscan(const int* __restrict__ bsum,
                                                int* __restrict__ bsum_off,
                                                int* __restrict__ total_out, int NB) {
    __shared__ int s[1024];
    int t = threadIdx.x;
    s[t] = (t < NB) ? bsum[t] : 0;
    __syncthreads();
    for (int d = 1; d < 1024; d <<= 1) {
        int v = (t >= d) ? s[t - d] : 0;
        __syncthreads();
        s[t] += v;
        __syncthreads();
    }
    if (t < NB) bsum_off[t] = (t == 0) ? 0 : s[t - 1];
    if (t == 0 && total_out) *total_out = s[1023];
}

__global__ __launch_bounds__(SCB) void k_boff(const int* __restrict__ v,
                                              const int* __restrict__ bsum_off,
                                              int* __restrict__ off, int M) {
    __shared__ int s[SCB];
    int t = threadIdx.x;
    int i = blockIdx.x * SCB + t;
    int myv = (i < M) ? v[i] : 0;
    s[t] = myv;
    __syncthreads();
    for (int d = 1; d < SCB; d <<= 1) {
        int u = (t >= d) ? s[t - d] : 0;
        __syncthreads();
        s[t] += u;
        __syncthreads();
    }
    if (i < M) off[i] = bsum_off[blockIdx.x] + s[t] - myv;  // exclusive
}

__global__ void k_fill(const int* __restrict__ src, const int* __restrict__ dst,
                       const float* __restrict__ dinv, const int* __restrict__ off4,
                       int* __restrict__ cur, float2* __restrict__ csr, int E, int cdiv) {
    int e = blockIdx.x * blockDim.x + threadIdx.x;
    if (e < E) {
        int d = dst[e], s = src[e];
        int key = d * 4 + s / cdiv;
        int pos = off4[key] + atomicAdd(&cur[key], 1);
        csr[pos] = make_float2(dinv[s] * dinv[d], __int_as_float(s));
    }
}

// ---------------- dense projection: bf16-split MFMA ----------------
// A-frag (m=lane&15, k=quad*8+j) == 8 contiguous floats of one x row ->
// direct global loads, full line use, no LDS, no scalar-W feed.
// x = xh + xl (bf16 each); D += Ah*Bh + Al*Bh + Ah*Bl  (err ~2^-17, fp32 acc)

__device__ inline unsigned bf16_rne(float f) {
    unsigned u = __float_as_uint(f);
    return (u + 0x7FFFu + ((u >> 16) & 1u)) >> 16;
}

__device__ inline void split8(const float* __restrict__ p, short8& hi, short8& lo) {
    float4 v0 = *(const float4*)p;
    float4 v1 = *(const float4*)(p + 4);
    float f[8] = {v0.x, v0.y, v0.z, v0.w, v1.x, v1.y, v1.z, v1.w};
#pragma unroll
    for (int j = 0; j < 8; j++) {
        unsigned hb = bf16_rne(f[j]);
        float fh = __uint_as_float(hb << 16);
        unsigned lb = bf16_rne(f[j] - fh);
        hi[j] = (short)hb;
        lo[j] = (short)lb;
    }
}

__global__ __launch_bounds__(256) void k_gemm3(const float* __restrict__ x,
                                               const float* __restrict__ W,
                                               const float* __restrict__ bias,
                                               float* __restrict__ h, int N) {
    int wave = threadIdx.x >> 6;
    int lane = threadIdx.x & 63;
    int m = lane & 15;
    int quad = lane >> 4;
    int nodeBase = blockIdx.x * 64 + wave * 16;

    int nodeA = nodeBase + m; if (nodeA >= N) nodeA = N - 1;  // clamp (loads only)
    const float* xrow = x + (size_t)nodeA * IN_DIM + quad * 8;
    const float* w0r = W + (size_t)m * IN_DIM + quad * 8;          // outs 0..15
    const float* w1r = W + (size_t)(m + 16) * IN_DIM + quad * 8;   // outs 16..31

    floatx4 acc0 = {0.f, 0.f, 0.f, 0.f};
    floatx4 acc1 = {0.f, 0.f, 0.f, 0.f};

    for (int kc = 0; kc < IN_DIM / 32; kc++) {
        short8 Ah, Al, B0h, B0l, B1h, B1l;
        split8(xrow + kc * 32, Ah, Al);
        split8(w0r + kc * 32, B0h, B0l);
        split8(w1r + kc * 32, B1h, B1l);
        acc0 = __builtin_amdgcn_mfma_f32_16x16x32_bf16(Ah, B0h, acc0, 0, 0, 0);
        acc1 = __builtin_amdgcn_mfma_f32_16x16x32_bf16(Ah, B1h, acc1, 0, 0, 0);
        acc0 = __builtin_amdgcn_mfma_f32_16x16x32_bf16(Al, B0h, acc0, 0, 0, 0);
        acc1 = __builtin_amdgcn_mfma_f32_16x16x32_bf16(Al, B1h, acc1, 0, 0, 0);
        acc0 = __builtin_amdgcn_mfma_f32_16x16x32_bf16(Ah, B0l, acc0, 0, 0, 0);
        acc1 = __builtin_amdgcn_mfma_f32_16x16x32_bf16(Ah, B1l, acc1, 0, 0, 0);
    }

    // C/D layout: col = lane&15 (out), row = quad*4 + reg (node)
    float b0 = bias[m], b1 = bias[16 + m];
#pragma unroll
    for (int r = 0; r < 4; r++) {
        int node = nodeBase + quad * 4 + r;
        if (node < N) {
            h[(size_t)node * OUT_DIM + m]      = acc0[r] + b0;
            h[(size_t)node * OUT_DIM + 16 + m] = acc1[r] + b1;
        }
    }
}

// ---------------- propagation: pull, float4/lane, node order ----------------

__global__ __launch_bounds__(256) void k_pull(const int* __restrict__ off4,
                                              const float2* __restrict__ csr,
                                              const float* __restrict__ zprev,
                                              const float* __restrict__ h,
                                              const float* __restrict__ dinv,
                                              float* __restrict__ znext, int N) {
    int t = blockIdx.x * 256 + threadIdx.x;
    int node = t >> 3;
    int l = (t & 7) * 4;
    if (node >= N) return;
    int beg = off4[node * 4];
    int end = off4[node * 4 + 4];
    float a00 = 0.f, a01 = 0.f, a02 = 0.f, a03 = 0.f;
    float a10 = 0.f, a11 = 0.f, a12 = 0.f, a13 = 0.f;
    int j = beg;
    for (; j + 2 <= end; j += 2) {
        float2 r0 = csr[j];
        float2 r1 = csr[j + 1];
        float4 z0 = *(const float4*)(zprev + (size_t)__float_as_int(r0.y) * OUT_DIM + l);
        float4 z1 = *(const float4*)(zprev + (size_t)__float_as_int(r1.y) * OUT_DIM + l);
        a00 = fmaf(r0.x, z0.x, a00); a01 = fmaf(r0.x, z0.y, a01);
        a02 = fmaf(r0.x, z0.z, a02); a03 = fmaf(r0.x, z0.w, a03);
        a10 = fmaf(r1.x, z1.x, a10); a11 = fmaf(r1.x, z1.y, a11);
        a12 = fmaf(r1.x, z1.z, a12); a13 = fmaf(r1.x, z1.w, a13);
    }
    if (j < end) {
        float2 r = csr[j];
        float4 z = *(const float4*)(zprev + (size_t)__float_as_int(r.y) * OUT_DIM + l);
        a00 = fmaf(r.x, z.x, a00); a01 = fmaf(r.x, z.y, a01);
        a02 = fmaf(r.x, z.z, a02); a03 = fmaf(r.x, z.w, a03);
    }
    float d = dinv[node];
    float d2 = d * d;
    float4 zs = *(const float4*)(zprev + (size_t)node * OUT_DIM + l);
    float4 hh = *(const float4*)(h + (size_t)node * OUT_DIM + l);
    float s0 = a00 + a10 + d2 * zs.x;
    float s1 = a01 + a11 + d2 * zs.y;
    float s2 = a02 + a12 + d2 * zs.z;
    float s3 = a03 + a13 + d2 * zs.w;
    float4 res = make_float4(fmaf(1.0f - ALPHA, s0, ALPHA * hh.x),
                             fmaf(1.0f - ALPHA, s1, ALPHA * hh.y),
                             fmaf(1.0f - ALPHA, s2, ALPHA * hh.z),
                             fmaf(1.0f - ALPHA, s3, ALPHA * hh.w));
    *(float4*)(znext + (size_t)node * OUT_DIM + l) = res;
}

extern "C" void kernel_launch(void* const* d_in, const int* in_sizes, int n_in,
                              void* d_out, int out_size, void* d_ws, size_t ws_size,
                              hipStream_t stream) {
    const float* x    = (const float*)d_in[0];
    const float* W    = (const float*)d_in[1];
    const float* bias = (const float*)d_in[2];
    const int*   ei   = (const int*)d_in[3];

    const int N = in_sizes[0] / IN_DIM;   // 100000
    const int E = in_sizes[3] / 2;        // 1600000
    const int* src = ei;
    const int* dst = ei + E;
    const int cdiv = (N + 3) / 4;
    const int M = 4 * N;                  // scan length
    const int NB = (M + SCB - 1) / SCB;   // 782 <= 1024

    // workspace layout
    char* ws = (char*)d_ws;
    size_t o = 0;
    float*  h    = (float*)(ws + o);  o += (size_t)N * OUT_DIM * 4;
    float*  A    = (float*)(ws + o);  o += (size_t)N * OUT_DIM * 4;
    float2* csr  = (float2*)(ws + o); o += (size_t)E * 8;
    float*  dinv = (float*)(ws + o);  o += (size_t)N * 4;
    int*    off4 = (int*)(ws + o);    o += (size_t)(M + 1) * 4;
    int*    cnt  = (int*)(ws + o);    o += (size_t)M * 4;
    int*    cur  = (int*)(ws + o);    o += (size_t)M * 4;
    int*    bsum = (int*)(ws + o);    o += (size_t)NB * 4;
    int*    boff = (int*)(ws + o);    o += (size_t)NB * 4;

    const int B = 256;
    int gN = (N + B - 1) / B;
    int gE = (E + B - 1) / B;
    int gP = ((size_t)N * 8 + B - 1) / B;   // pull grid (3125)
    int gG = (N + 63) / 64;                 // gemm grid (1563)

    hipMemsetAsync(cnt, 0, (size_t)2 * M * 4, stream);  // cnt + cur (adjacent)

    // degree + norm + chunked CSR
    k_count<<<gE, B, 0, stream>>>(src, dst, cnt, E, cdiv);
    k_rsqrt<<<gN, B, 0, stream>>>(cnt, dinv, N);
    k_bsum<<<NB, SCB, 0, stream>>>(cnt, bsum, M);
    k_bscan<<<1, 1024, 0, stream>>>(bsum, boff, off4 + M, NB);
    k_boff<<<NB, SCB, 0, stream>>>(cnt, boff, off4, M);
    k_fill<<<gE, B, 0, stream>>>(src, dst, dinv, off4, cur, csr, E, cdiv);

    // dense projection (bf16-split MFMA)
    k_gemm3<<<gG, B, 0, stream>>>(x, W, bias, h, N);

    // K propagation steps; ping-pong A <-> d_out so step 10 lands in d_out
    const float* zprev = h;
    for (int s = 0; s < KSTEPS; s++) {
        float* znext = (s % 2 == 0) ? A : (float*)d_out;
        k_pull<<<gP, B, 0, stream>>>(off4, csr, zprev, h, dinv, znext, N);
        zprev = znext;
    }
}